// Round 5
// baseline (32955.942 us; speedup 1.0000x reference)
//
#include <hip/hip_runtime.h>
#include <math.h>

#define Bb   256
#define Tt   512
#define INn  64
#define Hh   512
#define OUTn 96
#define NWG  256
#define TPB  1024
#define SP   (Hh*Bb)   // one state plane in floats
#define RSTRIDE 36     // reduction row stride (floats), 16B-aligned
#define HDR  8192      // ws header dwords: flags[256*16] + rel @4096, padded

struct Params {
  const float *Xt;          // [T][IN][B]
  float *H0, *H1;           // [2][H][B] each (ping-pong)
  unsigned int *flags;      // [NWG][16] padded arrival flags
  unsigned int *rel;        // single release word
  const float *Wih0,*Whh0,*bih0,*bhh0,*Wih1,*Whh1,*bih1,*bhh1;
  const float *dWih0,*dWhh0,*dbih0,*dbhh0,*dWih1,*dWhh1,*dbih1,*dbhh1;
  const float *projW,*projb;
  float *out;               // [B][OUT]
};

__device__ __forceinline__ float sigm(float x){ return 1.0f/(1.0f + expf(-x)); }

// Contention-free grid barrier (proven R4): per-WG padded arrival flags +
// single release word; WG0 threads 0..255 poll one flag each.
__device__ __forceinline__ void gridbar(unsigned int* flags, unsigned int* rel,
                                        unsigned int g) {
  __syncthreads();
  const int tid = threadIdx.x;
  if (blockIdx.x == 0) {
    if (tid > 0 && tid < NWG) {
      while (__hip_atomic_load(&flags[tid*16], __ATOMIC_RELAXED, __HIP_MEMORY_SCOPE_AGENT) < g)
        __builtin_amdgcn_s_sleep(1);
    }
    __syncthreads();
    if (tid == 0) {
      __threadfence();
      __hip_atomic_store(rel, g, __ATOMIC_RELEASE, __HIP_MEMORY_SCOPE_AGENT);
    }
    __syncthreads();
  } else {
    if (tid == 0) {
      __threadfence();
      __hip_atomic_store(&flags[blockIdx.x*16], g, __ATOMIC_RELEASE, __HIP_MEMORY_SCOPE_AGENT);
      while (__hip_atomic_load(rel, __ATOMIC_RELAXED, __HIP_MEMORY_SCOPE_AGENT) < g)
        __builtin_amdgcn_s_sleep(1);
      __threadfence();
    }
    __syncthreads();
  }
}

// Transpose inputs [B][T][IN] -> Xt [T][IN][B]
__global__ void __launch_bounds__(256) xpose(const float* __restrict__ X, float* __restrict__ Xt) {
  __shared__ float tile[64][65];
  const int t = blockIdx.x;
  const int l = threadIdx.x & 63;
  const int r = threadIdx.x >> 6;   // 0..3
  for (int qd = 0; qd < 4; ++qd) {
    #pragma unroll
    for (int rep = 0; rep < 16; ++rep) {
      int bl = rep*4 + r;
      tile[bl][l] = X[(size_t)(qd*64 + bl)*(Tt*INn) + (size_t)t*INn + l];
    }
    __syncthreads();
    #pragma unroll
    for (int rep = 0; rep < 16; ++rep) {
      int i = rep*4 + r;
      Xt[(size_t)t*(INn*Bb) + (size_t)i*Bb + qd*64 + l] = tile[l][i];
    }
    __syncthreads();
  }
}

// Persistent cooperative kernel. WG w owns hidden units {2w, 2w+1}.
// Thread layout (1024 threads):
//   bq = tid&63        batch-quad; thread handles batches 4*bq..4*bq+3
//   h  = (tid>>6)&1    which of the 2 units
//   kh = tid>>7        K-split 0..7; each handles 64 of the 512 K-rows
// Two-stage LDS reduction over kh (4 buffers): kh>=4 write RED[kh-4];
// sync; kh<4 absorb RED[kh], kh 1..3 write back RED[kh]; sync; kh0 final.
__global__ void __launch_bounds__(TPB) lstm_main(Params P) {
  __shared__ float WA[512][16];  // enc: [k][h*8 + (0..3: Wih1 ifgo | 4..7: Whh0 ifgo)]
  __shared__ float WB[512][8];   // enc: [k][h*4+g] Whh1 ; dec: dWhh0
  __shared__ float WX[64][8];    // enc: [k][h*4+g] Wih0
  __shared__ float BS[16];
  __shared__ float PW[Hh];
  __shared__ float WXD[8];
  __shared__ float PBs;
  __shared__ float RED[4][128][RSTRIDE];

  const int tid = threadIdx.x;
  const int w   = blockIdx.x;
  const int bq  = tid & 63;
  const int h   = (tid >> 6) & 1;
  const int kh  = tid >> 7;          // 0..7
  const int j   = 2*w + h;
  const int h8  = h*8, h4 = h*4;
  const int slot = h*64 + bq;        // 0..127
  const int b4  = 4*bq;
  unsigned int bg = 1;

  // ---------------- encoder weight load ----------------
  for (int e = tid; e < 512*16; e += TPB) {
    int k = e >> 4, c = e & 15, hh = c >> 3, s = c & 7;
    int unit = 2*w + hh;
    WA[k][c] = (s < 4) ? P.Wih1[(size_t)(s*Hh + unit)*Hh + k]
                       : P.Whh0[(size_t)((s-4)*Hh + unit)*Hh + k];
  }
  for (int e = tid; e < 512*8; e += TPB) {
    int k = e >> 3, c = e & 7, hh = c >> 2, g = c & 3;
    WB[k][c] = P.Whh1[(size_t)(g*Hh + 2*w + hh)*Hh + k];
  }
  for (int e = tid; e < 64*8; e += TPB) {
    int k = e >> 3, c = e & 7, hh = c >> 2, g = c & 3;
    WX[k][c] = P.Wih0[(size_t)(g*Hh + 2*w + hh)*INn + k];
  }
  if (tid < 16) {
    int c = tid, hh = c >> 3, s = c & 7;
    int unit = 2*w + hh;
    BS[c] = (s < 4) ? (P.bih1[s*Hh+unit] + P.bhh1[s*Hh+unit])
                    : (P.bih0[(s-4)*Hh+unit] + P.bhh0[(s-4)*Hh+unit]);
  }
  __syncthreads();

  float c0[4] = {0,0,0,0}, c1[4] = {0,0,0,0};

  // ---------------- encoder phases ----------------
  for (int p = -1; p <= 511; ++p) {
    // z[g][m]: g = 0..3 cell1 ifgo, 4..7 cell0 ifgo
    float z[8][4];
    #pragma unroll
    for (int g = 0; g < 8; ++g)
      #pragma unroll
      for (int m = 0; m < 4; ++m)
        z[g][m] = (kh==0) ? BS[h8+g] : 0.f;

    const float* __restrict__ h0in = P.H0 + (size_t)(p & 1)*SP + b4;       // h0(p)
    const float* __restrict__ h1in = P.H1 + (size_t)((p+1) & 1)*SP + b4;   // h1(p-1)
    const int kb = kh*64, ke = kb + 64;
    #pragma unroll 4
    for (int k = kb; k < ke; ++k) {
      const float4 w1 = *reinterpret_cast<const float4*>(&WA[k][h8]);
      const float4 w0 = *reinterpret_cast<const float4*>(&WA[k][h8+4]);
      const float4 wb = *reinterpret_cast<const float4*>(&WB[k][h4]);
      const float4 hv4 = *reinterpret_cast<const float4*>(&h0in[k*Bb]);
      const float4 gv4 = *reinterpret_cast<const float4*>(&h1in[k*Bb]);
      const float* hv = &hv4.x;
      const float* gv = &gv4.x;
      #pragma unroll
      for (int m = 0; m < 4; ++m) {
        z[0][m]=fmaf(w1.x,hv[m],z[0][m]); z[1][m]=fmaf(w1.y,hv[m],z[1][m]);
        z[2][m]=fmaf(w1.z,hv[m],z[2][m]); z[3][m]=fmaf(w1.w,hv[m],z[3][m]);
        z[4][m]=fmaf(w0.x,hv[m],z[4][m]); z[5][m]=fmaf(w0.y,hv[m],z[5][m]);
        z[6][m]=fmaf(w0.z,hv[m],z[6][m]); z[7][m]=fmaf(w0.w,hv[m],z[7][m]);
        z[0][m]=fmaf(wb.x,gv[m],z[0][m]); z[1][m]=fmaf(wb.y,gv[m],z[1][m]);
        z[2][m]=fmaf(wb.z,gv[m],z[2][m]); z[3][m]=fmaf(wb.w,gv[m],z[3][m]);
      }
    }
    { // x-part: 8 K-rows per kh group
      int tx = (p+1 < Tt) ? (p+1) : (Tt-1);
      const float* __restrict__ xin = P.Xt + (size_t)tx*(INn*Bb) + b4;
      #pragma unroll
      for (int k = kh*8; k < kh*8 + 8; ++k) {
        const float4 wv = *reinterpret_cast<const float4*>(&WX[k][h4]);
        const float4 xv4 = *reinterpret_cast<const float4*>(&xin[k*Bb]);
        const float* xv = &xv4.x;
        #pragma unroll
        for (int m = 0; m < 4; ++m) {
          z[4][m]=fmaf(wv.x,xv[m],z[4][m]); z[5][m]=fmaf(wv.y,xv[m],z[5][m]);
          z[6][m]=fmaf(wv.z,xv[m],z[6][m]); z[7][m]=fmaf(wv.w,xv[m],z[7][m]);
        }
      }
    }
    // two-stage kh reduction (32 floats per slot)
    if (kh >= 4) {
      float* r = &RED[kh-4][slot][0];
      #pragma unroll
      for (int g = 0; g < 8; ++g)
        *reinterpret_cast<float4*>(&r[g*4]) = make_float4(z[g][0],z[g][1],z[g][2],z[g][3]);
    }
    __syncthreads();
    if (kh < 4) {
      float* r = &RED[kh][slot][0];
      #pragma unroll
      for (int g = 0; g < 8; ++g) {
        const float4 v = *reinterpret_cast<const float4*>(&r[g*4]);
        z[g][0]+=v.x; z[g][1]+=v.y; z[g][2]+=v.z; z[g][3]+=v.w;
      }
      if (kh > 0) {
        #pragma unroll
        for (int g = 0; g < 8; ++g)
          *reinterpret_cast<float4*>(&r[g*4]) = make_float4(z[g][0],z[g][1],z[g][2],z[g][3]);
      }
    }
    __syncthreads();
    if (kh == 0) {
      #pragma unroll
      for (int t = 1; t < 4; ++t) {
        const float* r = &RED[t][slot][0];
        #pragma unroll
        for (int g = 0; g < 8; ++g)
          #pragma unroll
          for (int m = 0; m < 4; ++m) z[g][m] += r[g*4+m];
      }
      if (p >= 0) {
        float* st = P.H1 + (size_t)(p & 1)*SP + (size_t)j*Bb + b4;
        float4 o; float* ov = &o.x;
        #pragma unroll
        for (int m = 0; m < 4; ++m) {
          c1[m] = sigm(z[1][m])*c1[m] + sigm(z[0][m])*tanhf(z[2][m]);
          ov[m] = sigm(z[3][m])*tanhf(c1[m]);
        }
        *reinterpret_cast<float4*>(st) = o;
      }
      if (p < 511) {
        float* st = P.H0 + (size_t)((p+1) & 1)*SP + (size_t)j*Bb + b4;
        float4 o; float* ov = &o.x;
        #pragma unroll
        for (int m = 0; m < 4; ++m) {
          c0[m] = sigm(z[5][m])*c0[m] + sigm(z[4][m])*tanhf(z[6][m]);
          ov[m] = sigm(z[7][m])*tanhf(c0[m]);
        }
        *reinterpret_cast<float4*>(st) = o;
      }
    }
    gridbar(P.flags, P.rel, bg); ++bg;
  }

  // ---------------- decoder weight load ----------------
  for (int e = tid; e < 512*16; e += TPB) {
    int k = e >> 4, c = e & 15, hh = c >> 3, s = c & 7;
    int unit = 2*w + hh;
    WA[k][c] = (s < 4) ? P.dWih1[(size_t)(s*Hh + unit)*Hh + k]
                       : P.dWhh1[(size_t)((s-4)*Hh + unit)*Hh + k];
  }
  for (int e = tid; e < 512*8; e += TPB) {
    int k = e >> 3, c = e & 7, hh = c >> 2, g = c & 3;
    WB[k][c] = P.dWhh0[(size_t)(g*Hh + 2*w + hh)*Hh + k];
  }
  if (tid < 8) {
    int c = tid, hh = c >> 2, g = c & 3;
    WXD[c] = P.dWih0[g*Hh + 2*w + hh];
  }
  if (tid >= 16 && tid < 32) {
    int c = tid - 16, hh = c >> 3, s = c & 7;
    int unit = 2*w + hh;
    BS[c] = (s < 4) ? (P.dbih1[s*Hh+unit] + P.dbhh1[s*Hh+unit])
                    : (P.dbih0[(s-4)*Hh+unit] + P.dbhh0[(s-4)*Hh+unit]);
  }
  for (int k = tid; k < Hh; k += TPB) PW[k] = P.projW[k];
  if (tid == 0) PBs = P.projb[0];
  __syncthreads();

  // ---------------- decoder ----------------
  for (int q = 0; q < OUTn; ++q) {
    // ---- phase A: cell0d(q). x(q) = (q==0) ? 0 : proj(h1d(q-1)) ----
    float xq[4] = {0,0,0,0};
    if (kh == 0 && q > 0) {
      const float* __restrict__ h1p = P.H1 + (size_t)((q+1)&1)*SP + b4;
      float acc[4] = {PBs, PBs, PBs, PBs};
      #pragma unroll 4
      for (int k = 0; k < Hh; ++k) {
        float pw = PW[k];
        const float4 hp4 = *reinterpret_cast<const float4*>(&h1p[k*Bb]);
        const float* hp = &hp4.x;
        #pragma unroll
        for (int m = 0; m < 4; ++m) acc[m] = fmaf(pw, hp[m], acc[m]);
      }
      #pragma unroll
      for (int m = 0; m < 4; ++m) xq[m] = acc[m];
      if (w == 0 && h == 0) {
        #pragma unroll
        for (int m = 0; m < 4; ++m) P.out[(size_t)(b4 + m)*OUTn + (q-1)] = xq[m];
      }
    }
    float zd[4][4];
    #pragma unroll
    for (int g = 0; g < 4; ++g)
      #pragma unroll
      for (int m = 0; m < 4; ++m)
        zd[g][m] = (kh==0) ? fmaf(WXD[h4+g], xq[m], BS[h8+4+g]) : 0.f;
    {
      const float* __restrict__ h0p = P.H0 + (size_t)((q+1)&1)*SP + b4;  // h0d(q-1)
      const int kb = kh*64, ke = kb + 64;
      #pragma unroll 4
      for (int k = kb; k < ke; ++k) {
        const float4 wv = *reinterpret_cast<const float4*>(&WB[k][h4]);
        const float4 hv4 = *reinterpret_cast<const float4*>(&h0p[k*Bb]);
        const float* hv = &hv4.x;
        #pragma unroll
        for (int m = 0; m < 4; ++m) {
          zd[0][m]=fmaf(wv.x,hv[m],zd[0][m]); zd[1][m]=fmaf(wv.y,hv[m],zd[1][m]);
          zd[2][m]=fmaf(wv.z,hv[m],zd[2][m]); zd[3][m]=fmaf(wv.w,hv[m],zd[3][m]);
        }
      }
    }
    if (kh >= 4) {
      float* r = &RED[kh-4][slot][0];
      #pragma unroll
      for (int g = 0; g < 4; ++g)
        *reinterpret_cast<float4*>(&r[g*4]) = make_float4(zd[g][0],zd[g][1],zd[g][2],zd[g][3]);
    }
    __syncthreads();
    if (kh < 4) {
      float* r = &RED[kh][slot][0];
      #pragma unroll
      for (int g = 0; g < 4; ++g) {
        const float4 v = *reinterpret_cast<const float4*>(&r[g*4]);
        zd[g][0]+=v.x; zd[g][1]+=v.y; zd[g][2]+=v.z; zd[g][3]+=v.w;
      }
      if (kh > 0) {
        #pragma unroll
        for (int g = 0; g < 4; ++g)
          *reinterpret_cast<float4*>(&r[g*4]) = make_float4(zd[g][0],zd[g][1],zd[g][2],zd[g][3]);
      }
    }
    __syncthreads();
    if (kh == 0) {
      #pragma unroll
      for (int t = 1; t < 4; ++t) {
        const float* r = &RED[t][slot][0];
        #pragma unroll
        for (int g = 0; g < 4; ++g)
          #pragma unroll
          for (int m = 0; m < 4; ++m) zd[g][m] += r[g*4+m];
      }
      float* st = P.H0 + (size_t)(q&1)*SP + (size_t)j*Bb + b4;
      float4 o; float* ov = &o.x;
      #pragma unroll
      for (int m = 0; m < 4; ++m) {
        c0[m] = sigm(zd[1][m])*c0[m] + sigm(zd[0][m])*tanhf(zd[2][m]);
        ov[m] = sigm(zd[3][m])*tanhf(c0[m]);
      }
      *reinterpret_cast<float4*>(st) = o;
    }
    gridbar(P.flags, P.rel, bg); ++bg;

    // ---- phase B: cell1d(q) ----
    float y[4][4];
    #pragma unroll
    for (int g = 0; g < 4; ++g)
      #pragma unroll
      for (int m = 0; m < 4; ++m)
        y[g][m] = (kh==0) ? BS[h8+g] : 0.f;
    {
      const float* __restrict__ h0c = P.H0 + (size_t)(q&1)*SP + b4;        // h0d(q)
      const float* __restrict__ h1q = P.H1 + (size_t)((q+1)&1)*SP + b4;    // h1d(q-1)
      const int kb = kh*64, ke = kb + 64;
      #pragma unroll 4
      for (int k = kb; k < ke; ++k) {
        const float4 w1 = *reinterpret_cast<const float4*>(&WA[k][h8]);
        const float4 w2 = *reinterpret_cast<const float4*>(&WA[k][h8+4]);
        const float4 av4 = *reinterpret_cast<const float4*>(&h0c[k*Bb]);
        const float4 dv4 = *reinterpret_cast<const float4*>(&h1q[k*Bb]);
        const float* av = &av4.x;
        const float* dv = &dv4.x;
        #pragma unroll
        for (int m = 0; m < 4; ++m) {
          y[0][m]=fmaf(w1.x,av[m],y[0][m]); y[1][m]=fmaf(w1.y,av[m],y[1][m]);
          y[2][m]=fmaf(w1.z,av[m],y[2][m]); y[3][m]=fmaf(w1.w,av[m],y[3][m]);
          y[0][m]=fmaf(w2.x,dv[m],y[0][m]); y[1][m]=fmaf(w2.y,dv[m],y[1][m]);
          y[2][m]=fmaf(w2.z,dv[m],y[2][m]); y[3][m]=fmaf(w2.w,dv[m],y[3][m]);
        }
      }
    }
    if (kh >= 4) {
      float* r = &RED[kh-4][slot][0];
      #pragma unroll
      for (int g = 0; g < 4; ++g)
        *reinterpret_cast<float4*>(&r[g*4]) = make_float4(y[g][0],y[g][1],y[g][2],y[g][3]);
    }
    __syncthreads();
    if (kh < 4) {
      float* r = &RED[kh][slot][0];
      #pragma unroll
      for (int g = 0; g < 4; ++g) {
        const float4 v = *reinterpret_cast<const float4*>(&r[g*4]);
        y[g][0]+=v.x; y[g][1]+=v.y; y[g][2]+=v.z; y[g][3]+=v.w;
      }
      if (kh > 0) {
        #pragma unroll
        for (int g = 0; g < 4; ++g)
          *reinterpret_cast<float4*>(&r[g*4]) = make_float4(y[g][0],y[g][1],y[g][2],y[g][3]);
      }
    }
    __syncthreads();
    if (kh == 0) {
      #pragma unroll
      for (int t = 1; t < 4; ++t) {
        const float* r = &RED[t][slot][0];
        #pragma unroll
        for (int g = 0; g < 4; ++g)
          #pragma unroll
          for (int m = 0; m < 4; ++m) y[g][m] += r[g*4+m];
      }
      float* st = P.H1 + (size_t)(q&1)*SP + (size_t)j*Bb + b4;
      float4 o; float* ov = &o.x;
      #pragma unroll
      for (int m = 0; m < 4; ++m) {
        c1[m] = sigm(y[1][m])*c1[m] + sigm(y[0][m])*tanhf(y[2][m]);
        ov[m] = sigm(y[3][m])*tanhf(c1[m]);
      }
      *reinterpret_cast<float4*>(st) = o;
    }
    gridbar(P.flags, P.rel, bg); ++bg;
  }

  // ---- final y(OUT-1) ----
  if (kh == 0 && w == 0 && h == 0) {
    const float* __restrict__ h1f = P.H1 + (size_t)((OUTn-1)&1)*SP + b4;
    float acc[4] = {PBs, PBs, PBs, PBs};
    #pragma unroll 4
    for (int k = 0; k < Hh; ++k) {
      float pw = PW[k];
      const float4 hp4 = *reinterpret_cast<const float4*>(&h1f[k*Bb]);
      const float* hp = &hp4.x;
      #pragma unroll
      for (int m = 0; m < 4; ++m) acc[m] = fmaf(pw, hp[m], acc[m]);
    }
    #pragma unroll
    for (int m = 0; m < 4; ++m) P.out[(size_t)(b4 + m)*OUTn + (OUTn-1)] = acc[m];
  }
}

extern "C" void kernel_launch(void* const* d_in, const int* in_sizes, int n_in,
                              void* d_out, int out_size, void* d_ws, size_t ws_size,
                              hipStream_t stream) {
  Params P;
  const float* X = (const float*)d_in[0];
  P.Wih0  = (const float*)d_in[1];  P.Whh0  = (const float*)d_in[2];
  P.bih0  = (const float*)d_in[3];  P.bhh0  = (const float*)d_in[4];
  P.Wih1  = (const float*)d_in[5];  P.Whh1  = (const float*)d_in[6];
  P.bih1  = (const float*)d_in[7];  P.bhh1  = (const float*)d_in[8];
  P.dWih0 = (const float*)d_in[9];  P.dWhh0 = (const float*)d_in[10];
  P.dbih0 = (const float*)d_in[11]; P.dbhh0 = (const float*)d_in[12];
  P.dWih1 = (const float*)d_in[13]; P.dWhh1 = (const float*)d_in[14];
  P.dbih1 = (const float*)d_in[15]; P.dbhh1 = (const float*)d_in[16];
  P.projW = (const float*)d_in[17]; P.projb = (const float*)d_in[18];

  float* ws = (float*)d_ws;
  P.flags = (unsigned int*)ws;          // [256][16] padded flags
  P.rel   = (unsigned int*)ws + 4096;   // release word (within HDR pad)
  P.H0  = ws + HDR;                     // [2][H][B]
  P.H1  = ws + HDR + 2*SP;              // [2][H][B]
  float* Xt = ws + HDR + 4*SP;          // [T][IN][B]
  P.Xt  = Xt;
  P.out = (float*)d_out;

  hipMemsetAsync(d_ws, 0, (size_t)(HDR + 4*SP)*sizeof(float), stream);
  hipLaunchKernelGGL(xpose, dim3(Tt), dim3(256), 0, stream, X, Xt);

  void* args[] = { &P };
  hipLaunchCooperativeKernel((void*)lstm_main, dim3(NWG), dim3(TPB), args, 0, stream);
}